// Round 13
// baseline (176.033 us; speedup 1.0000x reference)
//
#include <hip/hip_runtime.h>
#include <hip/hip_fp16.h>

#define NSET 38
#define NSNAP 9
#define PART (NSNAP*NSET*64)   // 21888 floats of partial per block
#define PPB 64
#define HSTR 72                // zth row stride (fp16): 144B rows, 16B-aligned
#define PSTR 66                // ztp row stride (half): 33-word rows, conflict-free
#define WHALF (8*64*64)        // fp16 weight elements

typedef unsigned int uint;
typedef __fp16 half8 __attribute__((ext_vector_type(8)));
typedef float  f32x4 __attribute__((ext_vector_type(4)));

#define HNEGINF 0xFC00u        // fp16 -inf bits

static __device__ __forceinline__ uint pk_add(uint a, uint b) {
  uint r;
  asm volatile("v_pk_add_f16 %0, %1, %2" : "=v"(r) : "v"(a), "v"(b));
  return r;
}
static __device__ __forceinline__ uint pk_max(uint a, uint b) {
  uint r;
  asm volatile("v_pk_max_f16 %0, %1, %2" : "=v"(r) : "v"(a), "v"(b));
  return r;
}
static __device__ __forceinline__ float half_lo_f(uint u) {
  return (float)__builtin_bit_cast(__fp16, (unsigned short)(u & 0xFFFFu));
}
static __device__ __forceinline__ float half_hi_f(uint u) {
  return (float)__builtin_bit_cast(__fp16, (unsigned short)(u >> 16));
}

// kA<CHUNKS>: 256 threads, PPB=64 points/chunk, grid 1024 -> 4 blocks/CU.
// conv0/prelu-s0: thread t -> point q=t&63, dim-quarter g (acc0[16]).
// Layers 1..8: per-wave MFMA 16x16x32 f16 (R11), A-frags via ONE ds_read_b128
// from zth[pt][dim] fp16. Pool: lane=dim, wave g = set-group (10/10/10/8),
// fp16x2 packed (2 points/lane-op) from ztp[dim][pt] + uint addend words
// (0 / -inf packed): per 2pts x 10 sets = 1 b32 + 10 uniform b32 +
// 10 v_pk_add_f16 + 10 v_pk_max_f16 (inline asm: ROCm 7.2 lacks __hmax2 on
// gfx950) — ~half of R11's 42 issue slots (R11: pool issue = whole kernel).
// LDS 27.4 KB -> allocator occupancy target 5 blocks/CU -> VGPR cap ~102
// >> ~70 live (LDS-as-governor, proven R3/R8/R10/R11).
template<int CHUNKS>
__global__ __launch_bounds__(256)
void kA(const int* __restrict__ x, const float* __restrict__ w0,
        const float* __restrict__ cw, const float* __restrict__ cb,
        const float* __restrict__ pa, const __fp16* __restrict__ wf,
        float* __restrict__ partial)
{
  __shared__ __fp16 zth[PPB * HSTR];     //  9216 B [pt][dim]  (MFMA A-side)
  __shared__ __fp16 ztp[64 * PSTR];      //  8448 B [dim][pt]  (pool side)
  __shared__ uint   addp[32 * 40];       //  5120 B [pt-pair][set-slot]
  __shared__ uint   memb2[PPB * 2];      //   512 B [pt][half]
  __shared__ float  padl[1024];          //  4096 B occupancy governor

  const int tid = threadIdx.x;
  const int q  = tid & 63;             // point (conv0) / dim (pool)
  const int g  = __builtin_amdgcn_readfirstlane(tid >> 6);  // wave id, uniform
  const int l  = tid & 63;
  const int lr = l & 15;               // mfma: A-row offset / B,C col (dim)
  const int lg = l >> 4;               // mfma: k-group / C row-group
  const int sbase = g * 10;            // set groups 10/10/10/8
  const int nset = (g == 3) ? 8 : 10;

  if ((int)blockIdx.x < 0) padl[tid] = 0.f;   // keep pad alive, never runs

  #pragma unroll 1
  for (int c = 0; c < CHUNKS; ++c) {
    const int p = (blockIdx.x * CHUNKS + c) * PPB + q;

    // membership halves: waves 0,1 load 19 set-rows each (coalesced)
    if (c) __syncthreads();            // prior chunk's LDS readers done
    if (tid < 128) {
      const int half = tid >> 6;
      uint m = 0;
      #pragma unroll
      for (int j = 0; j < 19; ++j)
        m |= (uint)(x[(half * 19 + j) * 65536 + p] == 1) << j;
      memb2[q * 2 + half] = m;
    }
    __syncthreads();

    // addp[pair][j]: lo half = pt even, hi half = pt odd; in-set ? 0 : -inf
    #pragma unroll
    for (int i = tid; i < 1280; i += 256) {
      int pr = i / 40, j = i - pr * 40;
      uint lo0 = memb2[(2 * pr) * 2],     hi0 = memb2[(2 * pr) * 2 + 1];
      uint lo1 = memb2[(2 * pr + 1) * 2], hi1 = memb2[(2 * pr + 1) * 2 + 1];
      uint b0 = (j < 19) ? ((lo0 >> j) & 1u) : (j < 38) ? ((hi0 >> (j - 19)) & 1u) : 0u;
      uint b1 = (j < 19) ? ((lo1 >> j) & 1u) : (j < 38) ? ((hi1 >> (j - 19)) & 1u) : 0u;
      addp[i] = (b0 ? 0u : HNEGINF) | ((b1 ? 0u : HNEGINF) << 16);
    }

    // conv0: pre-act dims [16g,16g+16) of point q; weights via s_load
    float acc0[16];
    {
      float px = -1.f + (2.f / 255.f) * (float)(p & 255);
      float py = -1.f + (2.f / 255.f) * (float)(p >> 8);
      #pragma unroll
      for (int d = 0; d < 16; ++d) {
        int dd = (g << 4) + d;
        acc0[d] = fmaf(px, w0[2 * dd], fmaf(py, w0[2 * dd + 1], cb[dd]));
      }
    }
    __syncthreads();                   // addp ready

    f32x4 Cf[4];                       // layer-(s) pre-act frags (s>=1)

    #pragma unroll 1
    for (int s = 0; s < NSNAP; ++s) {
      // prelu -> zth (fp16 [pt][dim]) + ztp (fp16 [dim][pt], pair-packed)
      if (s) __syncthreads();          // prev snapshot's readers done
      if (s == 0) {
        #pragma unroll
        for (int d = 0; d < 16; ++d) {
          int dd = (g << 4) + d;
          float zv = acc0[d];
          float a = pa[dd];
          float zp = zv > 0.f ? zv : a * zv;
          zth[q * HSTR + dd] = (__fp16)zp;
          ztp[dd * PSTR + q] = (__fp16)zp;
        }
      } else {
        // frag mapping: pt = 16g + 4*lg + r, dim = 16*dt + lr
        #pragma unroll
        for (int dt = 0; dt < 4; ++dt) {
          int dim = (dt << 4) + lr;
          float a = pa[(s << 6) + dim];
          __fp16 zp[4];
          #pragma unroll
          for (int r = 0; r < 4; ++r) {
            float zv = Cf[dt][r];
            zp[r] = (__fp16)(zv > 0.f ? zv : a * zv);
            zth[((g << 4) + (lg << 2) + r) * HSTR + dim] = zp[r];
          }
          int pt0 = (g << 4) + (lg << 2);
          __fp16* dst = &ztp[dim * PSTR + pt0];
          dst[0] = zp[0]; dst[1] = zp[1]; dst[2] = zp[2]; dst[3] = zp[3];
        }
      }
      __syncthreads();                 // this snapshot's zth/ztp ready

      // next layer via MFMA FIRST (latency hides under the pool below)
      if (s < 8) {
        half8 a0 = *(const half8*)&zth[((g << 4) + lr) * HSTR + (lg << 3)];
        half8 a1 = *(const half8*)&zth[((g << 4) + lr) * HSTR + 32 + (lg << 3)];
        const __fp16* wb = wf + ((size_t)s << 12);
        #pragma unroll
        for (int dt = 0; dt < 4; ++dt) {
          float bias = cb[((s + 1) << 6) + (dt << 4) + lr];
          f32x4 a4 = {bias, bias, bias, bias};
          half8 b0 = *(const half8*)&wb[(((dt << 4) + lr) << 6) + (lg << 3)];
          half8 b1 = *(const half8*)&wb[(((dt << 4) + lr) << 6) + 32 + (lg << 3)];
          a4 = __builtin_amdgcn_mfma_f32_16x16x32_f16(a0, b0, a4, 0, 0, 0);
          a4 = __builtin_amdgcn_mfma_f32_16x16x32_f16(a1, b1, a4, 0, 0, 0);
          Cf[dt] = a4;
        }
      }

      // pool: wave g pools its 10 (or 8) sets over 32 point-PAIRS; lane=dim.
      // per pair: 1 b32 (2 pts) + 10 uniform b32 + 10 pk_add + 10 pk_max.
      uint run2[10];
      #pragma unroll
      for (int j = 0; j < 10; ++j) run2[j] = HNEGINF | (HNEGINF << 16);
      #pragma unroll 2
      for (int pr = 0; pr < 32; ++pr) {
        uint v = *(const uint*)&ztp[q * PSTR + (pr << 1)];
        const uint* ap = &addp[pr * 40 + sbase];
        #pragma unroll
        for (int j = 0; j < 10; ++j)
          run2[j] = pk_max(run2[j], pk_add(v, ap[j]));
      }
      {
        float* pb = partial + (size_t)blockIdx.x * PART + s * (NSET * 64) + q;
        #pragma unroll
        for (int j = 0; j < 10; ++j) {
          if (j < nset) {              // uniform guard (wave 3: 8 sets)
            float mx = fmaxf(half_lo_f(run2[j]), half_hi_f(run2[j]));
            int set = sbase + j;
            if (CHUNKS == 1 || c == 0) pb[set * 64] = mx;
            else                       pb[set * 64] = fmaxf(pb[set * 64], mx);
          }
        }
      }
    }
  }
}

// one-shot: cw f32 -> fp16 (RNE) into workspace
__global__ __launch_bounds__(256) void kW(const float* __restrict__ cw,
                                          __fp16* __restrict__ wf)
{
  int i = blockIdx.x * 256 + threadIdx.x;
  if (i < WHALF) wf[i] = (__fp16)cw[i];
}

// stage-1 reduce: y-slice reduces nblk/32 block-partials, in-place into the
// slice's first block (each (y,idx) owns its slot; read-before-write per thread)
__global__ __launch_bounds__(256) void kB1(float* __restrict__ partial, int per)
{
  int idx = blockIdx.x * 256 + threadIdx.x;
  if (idx >= PART) return;
  float* p0 = partial + (size_t)blockIdx.y * per * PART + idx;
  float mx = -3e38f;
  #pragma unroll 8
  for (int b = 0; b < per; ++b)
    mx = fmaxf(mx, p0[(size_t)b * PART]);
  p0[0] = mx;
}

// stage-2: reduce 32 slices + zero-point chain (folded kZ, f32 exact) + feat
__global__ __launch_bounds__(256) void kB2(const float* __restrict__ partial,
    int per, const float* __restrict__ cw, const float* __restrict__ cb,
    const float* __restrict__ pa, float* __restrict__ feat)
{
  __shared__ float zl[64];
  __shared__ float zc[NSNAP][64];
  __shared__ float zp[NSNAP][64];
  int tid = threadIdx.x;
  int d = tid & 63;
  float z = cb[d];
  #pragma unroll 1
  for (int s = 0; s < NSNAP; ++s) {
    if (tid < 64) {
      zc[s][d] = z;
      float a = pa[(s << 6) + d];
      float v = z > 0.f ? z : a * z;
      zp[s][d] = v;
      zl[d] = v;
    }
    __syncthreads();
    if (s < 8) {
      if (tid < 64) {
        float a2 = cb[((s + 1) << 6) + d];
        for (int k = 0; k < 64; ++k)
          a2 = fmaf(zl[k], cw[(s << 12) + (d << 6) + k], a2);
        z = a2;
      }
    }
    __syncthreads();
  }

  int idx = blockIdx.x * 256 + tid;
  if (idx >= PART) return;
  int s = idx / (NSET * 64);
  int r = idx - s * (NSET * 64);
  int set = r >> 6;
  int dd = r & 63;
  float mx = -3e38f;
  #pragma unroll
  for (int y = 0; y < 32; ++y)
    mx = fmaxf(mx, partial[(size_t)y * per * PART + idx]);
  int b = set / 19, cc = set - b * 19;
  float even_v, odd_v;
  if (mx < -5e37f) {                 // empty set -> zero-point snapshot
    even_v = zc[s][dd];
    odd_v  = zp[s][dd];
  } else {
    odd_v = mx;                      // prelu-domain max
    float a = pa[(s << 6) + dd];
    even_v = mx > 0.f ? mx : mx / a; // inverse prelu
  }
  size_t fb = ((size_t)b * 18 + 2 * s) * 1216 + cc * 64 + dd;
  feat[fb] = even_v;
  feat[fb + 1216] = odd_v;
}

// out[b][17-lr][srow] = scale*<feat[b][lr], fcw[lr][srow]> + fcb[lr][srow]
__global__ __launch_bounds__(256) void kC(const float* __restrict__ feat,
    const float* __restrict__ fcw, const float* __restrict__ fcb,
    float* __restrict__ out)
{
  __shared__ float f0[1216], f1[1216];
  int lr = blockIdx.y;
  int chunk = blockIdx.x;       // 0..31, 16 rows each
  int tid = threadIdx.x;
  for (int i = tid; i < 1216; i += 256) {
    f0[i] = feat[(size_t)(0 * 18 + lr) * 1216 + i];
    f1[i] = feat[(size_t)(1 * 18 + lr) * 1216 + i];
  }
  __syncthreads();
  int wv = tid >> 6, lane = tid & 63;
  float scale = 1.f / sqrtf(1216.f);
  int l = 17 - lr;
  #pragma unroll 1
  for (int rr = 0; rr < 4; ++rr) {
    int srow = (chunk << 4) + (wv << 2) + rr;
    const float* wrow = fcw + ((size_t)lr * 512 + srow) * 1216;
    float pp0 = 0.f, pp1 = 0.f;
    #pragma unroll
    for (int k = 0; k < 19; ++k) {
      float w = wrow[(k << 6) + lane];
      pp0 = fmaf(w, f0[(k << 6) + lane], pp0);
      pp1 = fmaf(w, f1[(k << 6) + lane], pp1);
    }
    #pragma unroll
    for (int off = 32; off; off >>= 1) {
      pp0 += __shfl_xor(pp0, off, 64);
      pp1 += __shfl_xor(pp1, off, 64);
    }
    if (lane == 0) {
      float b = fcb[lr * 512 + srow];
      out[((size_t)0 * 18 + l) * 512 + srow] = fmaf(scale, pp0, b);
      out[((size_t)1 * 18 + l) * 512 + srow] = fmaf(scale, pp1, b);
    }
  }
}

extern "C" void kernel_launch(void* const* d_in, const int* in_sizes, int n_in,
                              void* d_out, int out_size, void* d_ws, size_t ws_size,
                              hipStream_t stream) {
  const int*   x   = (const int*)d_in[0];
  const float* w0  = (const float*)d_in[1];
  const float* cw  = (const float*)d_in[2];
  const float* cb  = (const float*)d_in[3];
  const float* pa  = (const float*)d_in[4];
  const float* fcw = (const float*)d_in[5];
  const float* fcb = (const float*)d_in[6];
  float* ws = (float*)d_ws;
  float* out = (float*)d_out;

  // tail: feat (43776 f32) + wf (32768 fp16 = 16384 f32 slots)
  const size_t tail = (size_t)2 * 18 * 1216 + WHALF / 2;
  #define NEED(n) (((size_t)(n) * PART + tail) * 4)

  int nblk;
  if      (ws_size >= NEED(1024)) nblk = 1024;
  else if (ws_size >= NEED(512))  nblk = 512;
  else                            nblk = 256;

  float* partial = ws;
  float* feat = ws + (size_t)nblk * PART;
  __fp16* wf = (__fp16*)(feat + (size_t)2 * 18 * 1216);
  const int per = nblk >> 5;    // blocks per kB1 y-slice (32 slices)

  hipLaunchKernelGGL(kW, dim3(WHALF / 256), dim3(256), 0, stream, cw, wf);

  if (nblk == 1024) {
    hipLaunchKernelGGL(kA<1>, dim3(1024), dim3(256), 0, stream,
                       x, w0, cw, cb, pa, wf, partial);
  } else if (nblk == 512) {
    hipLaunchKernelGGL(kA<2>, dim3(512), dim3(256), 0, stream,
                       x, w0, cw, cb, pa, wf, partial);
  } else {
    hipLaunchKernelGGL(kA<4>, dim3(256), dim3(256), 0, stream,
                       x, w0, cw, cb, pa, wf, partial);
  }

  hipLaunchKernelGGL(kB1, dim3(86, 32), dim3(256), 0, stream, partial, per);
  hipLaunchKernelGGL(kB2, dim3(86), dim3(256), 0, stream,
                     partial, per, cw, cb, pa, feat);
  hipLaunchKernelGGL(kC, dim3(32, 18), dim3(256), 0, stream, feat, fcw, fcb, out);
}

// Round 14
// 130.607 us; speedup vs baseline: 1.3478x; 1.3478x over previous
//
#include <hip/hip_runtime.h>
#include <hip/hip_fp16.h>

#define NSET 38
#define NSNAP 9
#define PART (NSNAP*NSET*64)   // 21888 floats of partial per block
#define PPB 64
#define HSTR 72                // zth row stride (fp16): 144B rows, 16B-aligned
#define PSTR 72                // ztp row stride (fp16): 144B rows, 16B-aligned
#define WHALF (8*64*64)        // fp16 weight elements

typedef unsigned int uint;
typedef __fp16 half8 __attribute__((ext_vector_type(8)));
typedef float  f32x4 __attribute__((ext_vector_type(4)));

#define HNEGINF 0xFC00u        // fp16 -inf bits

static __device__ __forceinline__ uint pk_add(uint a, uint b) {
  uint r;
  asm("v_pk_add_f16 %0, %1, %2" : "=v"(r) : "v"(a), "v"(b));
  return r;
}
static __device__ __forceinline__ uint pk_max(uint a, uint b) {
  uint r;
  asm("v_pk_max_f16 %0, %1, %2" : "=v"(r) : "v"(a), "v"(b));
  return r;
}
static __device__ __forceinline__ float half_lo_f(uint u) {
  return (float)__builtin_bit_cast(__fp16, (unsigned short)(u & 0xFFFFu));
}
static __device__ __forceinline__ float half_hi_f(uint u) {
  return (float)__builtin_bit_cast(__fp16, (unsigned short)(u >> 16));
}

// kA<CHUNKS>: 256 threads, PPB=64 points/chunk, grid 1024 -> 4 blocks/CU.
// R13 lesson: pool was LDS-PIPE-bound (352 b32 ds_reads/wave-snap ~ 2040cyc
// x 144 wave-snaps/CU = 122us = measured kA). Fix: b128 both streams.
//  - addp TRANSPOSED [set][pr] -> wave reads its 10 set-rows as uniform
//    ds_read_b128 (4 prs each): 80 b128 vs 320 b32.
//  - ztp stride 72 (144B rows, 16B-aligned): v for 4 pairs = 1 b128
//    (banks 4q mod 32 -> 2-way, free): 8 b128 vs 32 b32.
//  - pk ops as NON-volatile asm (R13's volatile pinned the scheduler).
// Layers 1..8: per-wave MFMA 16x16x32 f16 (R11). LDS 28.2 KB -> allocator
// occupancy target 5 blocks/CU -> VGPR cap ~102 >> ~80 live (LDS-as-governor,
// proven R3/R8/R10/R11/R13).
template<int CHUNKS>
__global__ __launch_bounds__(256)
void kA(const int* __restrict__ x, const float* __restrict__ w0,
        const float* __restrict__ cw, const float* __restrict__ cb,
        const float* __restrict__ pa, const __fp16* __restrict__ wf,
        float* __restrict__ partial)
{
  __shared__ __fp16 zth[PPB * HSTR];     //  9216 B [pt][dim]  (MFMA A-side)
  __shared__ __fp16 ztp[64 * PSTR];      //  9216 B [dim][pt]  (pool side)
  __shared__ uint   addp[40 * 32];       //  5120 B [set][pr]  (transposed!)
  __shared__ uint   memb2[PPB * 2];      //   512 B [pt][half]
  __shared__ float  padl[1024];          //  4096 B occupancy governor

  const int tid = threadIdx.x;
  const int q  = tid & 63;             // point (conv0) / dim (pool)
  const int g  = __builtin_amdgcn_readfirstlane(tid >> 6);  // wave id, uniform
  const int l  = tid & 63;
  const int lr = l & 15;               // mfma: A-row offset / B,C col (dim)
  const int lg = l >> 4;               // mfma: k-group / C row-group
  const int sbase = g * 10;            // set groups 10/10/10/8
  const int nset = (g == 3) ? 8 : 10;

  if ((int)blockIdx.x < 0) padl[tid] = 0.f;   // keep pad alive, never runs

  #pragma unroll 1
  for (int c = 0; c < CHUNKS; ++c) {
    const int p = (blockIdx.x * CHUNKS + c) * PPB + q;

    // membership halves: waves 0,1 load 19 set-rows each (coalesced)
    if (c) __syncthreads();            // prior chunk's LDS readers done
    if (tid < 128) {
      const int half = tid >> 6;
      uint m = 0;
      #pragma unroll
      for (int j = 0; j < 19; ++j)
        m |= (uint)(x[(half * 19 + j) * 65536 + p] == 1) << j;
      memb2[q * 2 + half] = m;
    }
    __syncthreads();

    // addp[j][pr]: lo half = pt 2pr, hi half = pt 2pr+1; in-set ? 0 : -inf
    #pragma unroll
    for (int i = tid; i < 1280; i += 256) {
      int j = i >> 5, pr = i & 31;
      uint lo0 = memb2[(2 * pr) * 2],     hi0 = memb2[(2 * pr) * 2 + 1];
      uint lo1 = memb2[(2 * pr + 1) * 2], hi1 = memb2[(2 * pr + 1) * 2 + 1];
      uint b0 = (j < 19) ? ((lo0 >> j) & 1u) : (j < 38) ? ((hi0 >> (j - 19)) & 1u) : 0u;
      uint b1 = (j < 19) ? ((lo1 >> j) & 1u) : (j < 38) ? ((hi1 >> (j - 19)) & 1u) : 0u;
      addp[i] = (b0 ? 0u : HNEGINF) | ((b1 ? 0u : HNEGINF) << 16);
    }

    // conv0: pre-act dims [16g,16g+16) of point q; weights via s_load
    float acc0[16];
    {
      float px = -1.f + (2.f / 255.f) * (float)(p & 255);
      float py = -1.f + (2.f / 255.f) * (float)(p >> 8);
      #pragma unroll
      for (int d = 0; d < 16; ++d) {
        int dd = (g << 4) + d;
        acc0[d] = fmaf(px, w0[2 * dd], fmaf(py, w0[2 * dd + 1], cb[dd]));
      }
    }
    __syncthreads();                   // addp ready

    f32x4 Cf[4];                       // layer-(s) pre-act frags (s>=1)

    #pragma unroll 1
    for (int s = 0; s < NSNAP; ++s) {
      // prelu -> zth (fp16 [pt][dim]) + ztp (fp16 [dim][pt])
      if (s) __syncthreads();          // prev snapshot's readers done
      if (s == 0) {
        #pragma unroll
        for (int d = 0; d < 16; ++d) {
          int dd = (g << 4) + d;
          float zv = acc0[d];
          float a = pa[dd];
          float zp = zv > 0.f ? zv : a * zv;
          zth[q * HSTR + dd] = (__fp16)zp;
          ztp[dd * PSTR + q] = (__fp16)zp;
        }
      } else {
        // frag mapping: pt = 16g + 4*lg + r, dim = 16*dt + lr
        #pragma unroll
        for (int dt = 0; dt < 4; ++dt) {
          int dim = (dt << 4) + lr;
          float a = pa[(s << 6) + dim];
          __fp16 zp[4];
          #pragma unroll
          for (int r = 0; r < 4; ++r) {
            float zv = Cf[dt][r];
            zp[r] = (__fp16)(zv > 0.f ? zv : a * zv);
            zth[((g << 4) + (lg << 2) + r) * HSTR + dim] = zp[r];
          }
          int pt0 = (g << 4) + (lg << 2);          // byte 8-aligned
          uint2 w2;
          w2.x = (uint)__builtin_bit_cast(unsigned short, zp[0]) |
                 ((uint)__builtin_bit_cast(unsigned short, zp[1]) << 16);
          w2.y = (uint)__builtin_bit_cast(unsigned short, zp[2]) |
                 ((uint)__builtin_bit_cast(unsigned short, zp[3]) << 16);
          *(uint2*)&ztp[dim * PSTR + pt0] = w2;
        }
      }
      __syncthreads();                 // this snapshot's zth/ztp ready

      // next layer via MFMA FIRST (latency hides under the pool below)
      if (s < 8) {
        half8 a0 = *(const half8*)&zth[((g << 4) + lr) * HSTR + (lg << 3)];
        half8 a1 = *(const half8*)&zth[((g << 4) + lr) * HSTR + 32 + (lg << 3)];
        const __fp16* wb = wf + ((size_t)s << 12);
        #pragma unroll
        for (int dt = 0; dt < 4; ++dt) {
          float bias = cb[((s + 1) << 6) + (dt << 4) + lr];
          f32x4 a4 = {bias, bias, bias, bias};
          half8 b0 = *(const half8*)&wb[(((dt << 4) + lr) << 6) + (lg << 3)];
          half8 b1 = *(const half8*)&wb[(((dt << 4) + lr) << 6) + 32 + (lg << 3)];
          a4 = __builtin_amdgcn_mfma_f32_16x16x32_f16(a0, b0, a4, 0, 0, 0);
          a4 = __builtin_amdgcn_mfma_f32_16x16x32_f16(a1, b1, a4, 0, 0, 0);
          Cf[dt] = a4;
        }
      }

      // pool: per 4-pr chunk: 1 v-b128 + 10 uniform addp-b128 + 40 pk_add
      // + 40 pk_max. run2[j] chains are 10-way ILP.
      uint run2[10];
      #pragma unroll
      for (int j = 0; j < 10; ++j) run2[j] = HNEGINF | (HNEGINF << 16);
      #pragma unroll 2
      for (int c4 = 0; c4 < 8; ++c4) {
        uint4 v4 = *(const uint4*)&ztp[q * PSTR + (c4 << 3)];   // 4 pairs
        #pragma unroll
        for (int j = 0; j < 10; ++j) {
          uint4 aj = *(const uint4*)&addp[((sbase + j) << 5) + (c4 << 2)];
          run2[j] = pk_max(run2[j], pk_add(v4.x, aj.x));
          run2[j] = pk_max(run2[j], pk_add(v4.y, aj.y));
          run2[j] = pk_max(run2[j], pk_add(v4.z, aj.z));
          run2[j] = pk_max(run2[j], pk_add(v4.w, aj.w));
        }
      }
      {
        float* pb = partial + (size_t)blockIdx.x * PART + s * (NSET * 64) + q;
        #pragma unroll
        for (int j = 0; j < 10; ++j) {
          if (j < nset) {              // uniform guard (wave 3: 8 sets)
            float mx = fmaxf(half_lo_f(run2[j]), half_hi_f(run2[j]));
            int set = sbase + j;
            if (CHUNKS == 1 || c == 0) pb[set * 64] = mx;
            else                       pb[set * 64] = fmaxf(pb[set * 64], mx);
          }
        }
      }
    }
  }
}

// one-shot: cw f32 -> fp16 (RNE) into workspace
__global__ __launch_bounds__(256) void kW(const float* __restrict__ cw,
                                          __fp16* __restrict__ wf)
{
  int i = blockIdx.x * 256 + threadIdx.x;
  if (i < WHALF) wf[i] = (__fp16)cw[i];
}

// stage-1 reduce: y-slice reduces nblk/32 block-partials, in-place into the
// slice's first block (each (y,idx) owns its slot; read-before-write per thread)
__global__ __launch_bounds__(256) void kB1(float* __restrict__ partial, int per)
{
  int idx = blockIdx.x * 256 + threadIdx.x;
  if (idx >= PART) return;
  float* p0 = partial + (size_t)blockIdx.y * per * PART + idx;
  float mx = -3e38f;
  #pragma unroll 8
  for (int b = 0; b < per; ++b)
    mx = fmaxf(mx, p0[(size_t)b * PART]);
  p0[0] = mx;
}

// stage-2: reduce 32 slices + zero-point chain (folded kZ, f32 exact) + feat
__global__ __launch_bounds__(256) void kB2(const float* __restrict__ partial,
    int per, const float* __restrict__ cw, const float* __restrict__ cb,
    const float* __restrict__ pa, float* __restrict__ feat)
{
  __shared__ float zl[64];
  __shared__ float zc[NSNAP][64];
  __shared__ float zp[NSNAP][64];
  int tid = threadIdx.x;
  int d = tid & 63;
  float z = cb[d];
  #pragma unroll 1
  for (int s = 0; s < NSNAP; ++s) {
    if (tid < 64) {
      zc[s][d] = z;
      float a = pa[(s << 6) + d];
      float v = z > 0.f ? z : a * z;
      zp[s][d] = v;
      zl[d] = v;
    }
    __syncthreads();
    if (s < 8) {
      if (tid < 64) {
        float a2 = cb[((s + 1) << 6) + d];
        for (int k = 0; k < 64; ++k)
          a2 = fmaf(zl[k], cw[(s << 12) + (d << 6) + k], a2);
        z = a2;
      }
    }
    __syncthreads();
  }

  int idx = blockIdx.x * 256 + tid;
  if (idx >= PART) return;
  int s = idx / (NSET * 64);
  int r = idx - s * (NSET * 64);
  int set = r >> 6;
  int dd = r & 63;
  float mx = -3e38f;
  #pragma unroll
  for (int y = 0; y < 32; ++y)
    mx = fmaxf(mx, partial[(size_t)y * per * PART + idx]);
  int b = set / 19, cc = set - b * 19;
  float even_v, odd_v;
  if (mx < -5e37f) {                 // empty set -> zero-point snapshot
    even_v = zc[s][dd];
    odd_v  = zp[s][dd];
  } else {
    odd_v = mx;                      // prelu-domain max
    float a = pa[(s << 6) + dd];
    even_v = mx > 0.f ? mx : mx / a; // inverse prelu
  }
  size_t fb = ((size_t)b * 18 + 2 * s) * 1216 + cc * 64 + dd;
  feat[fb] = even_v;
  feat[fb + 1216] = odd_v;
}

// out[b][17-lr][srow] = scale*<feat[b][lr], fcw[lr][srow]> + fcb[lr][srow]
__global__ __launch_bounds__(256) void kC(const float* __restrict__ feat,
    const float* __restrict__ fcw, const float* __restrict__ fcb,
    float* __restrict__ out)
{
  __shared__ float f0[1216], f1[1216];
  int lr = blockIdx.y;
  int chunk = blockIdx.x;       // 0..31, 16 rows each
  int tid = threadIdx.x;
  for (int i = tid; i < 1216; i += 256) {
    f0[i] = feat[(size_t)(0 * 18 + lr) * 1216 + i];
    f1[i] = feat[(size_t)(1 * 18 + lr) * 1216 + i];
  }
  __syncthreads();
  int wv = tid >> 6, lane = tid & 63;
  float scale = 1.f / sqrtf(1216.f);
  int l = 17 - lr;
  #pragma unroll 1
  for (int rr = 0; rr < 4; ++rr) {
    int srow = (chunk << 4) + (wv << 2) + rr;
    const float* wrow = fcw + ((size_t)lr * 512 + srow) * 1216;
    float pp0 = 0.f, pp1 = 0.f;
    #pragma unroll
    for (int k = 0; k < 19; ++k) {
      float w = wrow[(k << 6) + lane];
      pp0 = fmaf(w, f0[(k << 6) + lane], pp0);
      pp1 = fmaf(w, f1[(k << 6) + lane], pp1);
    }
    #pragma unroll
    for (int off = 32; off; off >>= 1) {
      pp0 += __shfl_xor(pp0, off, 64);
      pp1 += __shfl_xor(pp1, off, 64);
    }
    if (lane == 0) {
      float b = fcb[lr * 512 + srow];
      out[((size_t)0 * 18 + l) * 512 + srow] = fmaf(scale, pp0, b);
      out[((size_t)1 * 18 + l) * 512 + srow] = fmaf(scale, pp1, b);
    }
  }
}

extern "C" void kernel_launch(void* const* d_in, const int* in_sizes, int n_in,
                              void* d_out, int out_size, void* d_ws, size_t ws_size,
                              hipStream_t stream) {
  const int*   x   = (const int*)d_in[0];
  const float* w0  = (const float*)d_in[1];
  const float* cw  = (const float*)d_in[2];
  const float* cb  = (const float*)d_in[3];
  const float* pa  = (const float*)d_in[4];
  const float* fcw = (const float*)d_in[5];
  const float* fcb = (const float*)d_in[6];
  float* ws = (float*)d_ws;
  float* out = (float*)d_out;

  // tail: feat (43776 f32) + wf (32768 fp16 = 16384 f32 slots)
  const size_t tail = (size_t)2 * 18 * 1216 + WHALF / 2;
  #define NEED(n) (((size_t)(n) * PART + tail) * 4)

  int nblk;
  if      (ws_size >= NEED(1024)) nblk = 1024;
  else if (ws_size >= NEED(512))  nblk = 512;
  else                            nblk = 256;

  float* partial = ws;
  float* feat = ws + (size_t)nblk * PART;
  __fp16* wf = (__fp16*)(feat + (size_t)2 * 18 * 1216);
  const int per = nblk >> 5;    // blocks per kB1 y-slice (32 slices)

  hipLaunchKernelGGL(kW, dim3(WHALF / 256), dim3(256), 0, stream, cw, wf);

  if (nblk == 1024) {
    hipLaunchKernelGGL(kA<1>, dim3(1024), dim3(256), 0, stream,
                       x, w0, cw, cb, pa, wf, partial);
  } else if (nblk == 512) {
    hipLaunchKernelGGL(kA<2>, dim3(512), dim3(256), 0, stream,
                       x, w0, cw, cb, pa, wf, partial);
  } else {
    hipLaunchKernelGGL(kA<4>, dim3(256), dim3(256), 0, stream,
                       x, w0, cw, cb, pa, wf, partial);
  }

  hipLaunchKernelGGL(kB1, dim3(86, 32), dim3(256), 0, stream, partial, per);
  hipLaunchKernelGGL(kB2, dim3(86), dim3(256), 0, stream,
                     partial, per, cw, cb, pa, feat);
  hipLaunchKernelGGL(kC, dim3(32, 18), dim3(256), 0, stream, feat, fcw, fcb, out);
}